// Round 8
// baseline (511.207 us; speedup 1.0000x reference)
//
#include <hip/hip_runtime.h>
#include <math.h>

// Problem dims: B=64, N=64, F=512, E=512, U=1024, V=32000
// ws layout (float offsets)
#define WS_S    0         // s   = so @ Q^T            (64 x 1024)
#define WS_W    65536     // w   = s @ K               (64 x 64)
#define WS_CTX  69632     // context                   (64 x 512)
#define WS_YE   102400    // ye  = emb[y]              (64 x 512)
#define WS_Z    135168    // z   = x@Wx + h@Wh + b     (64 x 4096)
#define WS_T1   397312    // t1  = h_new@W1 + b1       (64 x 1024)

// d_out layout (float offsets): (logits, h_new, h_new, c_new, aw)
#define OUT_LOGITS 0
#define OUT_H1     2048000
#define OUT_H2     2113536
#define OUT_C      2179072
#define OUT_AW     2244608

#define FMA4(ACC, A, W) { ACC.x += (A)*(W).x; ACC.y += (A)*(W).y; \
                          ACC.z += (A)*(W).z; ACC.w += (A)*(W).w; }

// 16 rows x 4 cols: A0..A3 = rows r0..r0+15 (broadcast), WV = 4 lane-cols
#define FMA16(WV, A0, A1, A2, A3) { \
    FMA4(acc[0],  A0.x, WV) FMA4(acc[1],  A0.y, WV) \
    FMA4(acc[2],  A0.z, WV) FMA4(acc[3],  A0.w, WV) \
    FMA4(acc[4],  A1.x, WV) FMA4(acc[5],  A1.y, WV) \
    FMA4(acc[6],  A1.z, WV) FMA4(acc[7],  A1.w, WV) \
    FMA4(acc[8],  A2.x, WV) FMA4(acc[9],  A2.y, WV) \
    FMA4(acc[10], A2.z, WV) FMA4(acc[11], A2.w, WV) \
    FMA4(acc[12], A3.x, WV) FMA4(acc[13], A3.y, WV) \
    FMA4(acc[14], A3.z, WV) FMA4(acc[15], A3.w, WV) }

// ---------------------------------------------------------------- K0: init
__global__ __launch_bounds__(256) void k0_init(const int* __restrict__ y,
    const float* __restrict__ emb, const float* __restrict__ b_lstm,
    const float* __restrict__ b1, float* __restrict__ ws) {
  int idx = blockIdx.x * 256 + threadIdx.x;      // 65536
  ws[WS_S + idx] = 0.f;
  ws[WS_T1 + idx] = b1[idx & 1023];
  *reinterpret_cast<float4*>(&ws[WS_Z + idx * 4]) =
      *reinterpret_cast<const float4*>(&b_lstm[(idx * 4) & 4095]);
  if (idx < 36864) ws[WS_W + idx] = 0.f;         // w + ctx (contiguous)
  if (idx < 32768) {
    int b = idx >> 9, e = idx & 511;
    ws[WS_YE + idx] = emb[(size_t)y[b] * 512 + e];
  }
}

// --------------------------------------------- KB2: logits <- b2 broadcast
// grid (125, 4): block = 256 cols x 16 rows, coalesced row-major stores.
__global__ __launch_bounds__(256) void kb2_init(const float* __restrict__ b2,
    float* __restrict__ out) {
  int n = blockIdx.x * 256 + threadIdx.x;
  int r0 = blockIdx.y * 16;
  float v = b2[n];
  float* p = out + OUT_LOGITS + (size_t)r0 * 32000 + n;
#pragma unroll
  for (int r = 0; r < 16; ++r) p[(size_t)r * 32000] = v;
}

// ------------------------------------------------- K1: s += so @ Q^T (atomic split-K)
__global__ __launch_bounds__(256) void k1_sgemm(const float* __restrict__ so,
    const float* __restrict__ Q, float* __restrict__ ws) {
  __shared__ float Qt[64][65];    // [k_l][u_l]
  __shared__ float SOt[64][68];   // [k_l][b]
  int u0 = blockIdx.x * 64;
  int k0 = blockIdx.y * 64;
  int tid = threadIdx.x;
  for (int i = 0; i < 16; ++i) {
    int idx = tid + i * 256;
    int r = idx >> 6, k_l = idx & 63;
    Qt[k_l][r]  = Q[(u0 + r) * 1024 + k0 + k_l];
    SOt[k_l][r] = so[r * 1024 + k0 + k_l];
  }
  __syncthreads();
  int u = tid & 63, g = tid >> 6;
  float acc[16];
#pragma unroll
  for (int j = 0; j < 16; ++j) acc[j] = 0.f;
  for (int k_l = 0; k_l < 64; ++k_l) {
    float qv = Qt[k_l][u];
    const float4* sp = reinterpret_cast<const float4*>(&SOt[k_l][g * 16]);
    float4 s0 = sp[0], s1 = sp[1], s2 = sp[2], s3 = sp[3];
    acc[0]  += s0.x * qv; acc[1]  += s0.y * qv; acc[2]  += s0.z * qv; acc[3]  += s0.w * qv;
    acc[4]  += s1.x * qv; acc[5]  += s1.y * qv; acc[6]  += s1.z * qv; acc[7]  += s1.w * qv;
    acc[8]  += s2.x * qv; acc[9]  += s2.y * qv; acc[10] += s2.z * qv; acc[11] += s2.w * qv;
    acc[12] += s3.x * qv; acc[13] += s3.y * qv; acc[14] += s3.z * qv; acc[15] += s3.w * qv;
  }
  float* s_out = ws + WS_S;
#pragma unroll
  for (int j = 0; j < 16; ++j)
    atomicAdd(&s_out[(g * 16 + j) * 1024 + u0 + u], acc[j]);
}

// ------------------------------------------------- K2: w += s @ K (atomic split-K)
__global__ __launch_bounds__(256) void k2_wgemm(const float* __restrict__ Katt,
    float* __restrict__ ws) {
  __shared__ float St[64][68];
  __shared__ float Kl[64][65];
  int k0 = blockIdx.x * 64;
  int tid = threadIdx.x;
  const float* s_in = ws + WS_S;
  for (int i = 0; i < 16; ++i) {
    int idx = tid + i * 256;
    int r = idx >> 6, q = idx & 63;
    St[q][r] = s_in[r * 1024 + k0 + q];
    Kl[r][q] = Katt[(k0 + r) * 64 + q];
  }
  __syncthreads();
  int n = tid & 63, g = tid >> 6;
  float acc[16];
#pragma unroll
  for (int j = 0; j < 16; ++j) acc[j] = 0.f;
  for (int k_l = 0; k_l < 64; ++k_l) {
    float kv = Kl[k_l][n];
    const float4* sp = reinterpret_cast<const float4*>(&St[k_l][g * 16]);
    float4 s0 = sp[0], s1 = sp[1], s2 = sp[2], s3 = sp[3];
    acc[0]  += s0.x * kv; acc[1]  += s0.y * kv; acc[2]  += s0.z * kv; acc[3]  += s0.w * kv;
    acc[4]  += s1.x * kv; acc[5]  += s1.y * kv; acc[6]  += s1.z * kv; acc[7]  += s1.w * kv;
    acc[8]  += s2.x * kv; acc[9]  += s2.y * kv; acc[10] += s2.z * kv; acc[11] += s2.w * kv;
    acc[12] += s3.x * kv; acc[13] += s3.y * kv; acc[14] += s3.z * kv; acc[15] += s3.w * kv;
  }
  float* w_out = ws + WS_W;
#pragma unroll
  for (int j = 0; j < 16; ++j)
    atomicAdd(&w_out[(g * 16 + j) * 64 + n], acc[j]);
}

// ---------------- K3: scores->softmax->aw + context. grid (i=64, set=8), 256 thr
__global__ __launch_bounds__(256) void k3_attn(const float* __restrict__ feat,
    float* __restrict__ ws, float* __restrict__ out) {
  __shared__ float wt[64][8];     // [n][j]
  __shared__ float red[32];       // 4 waves x 8
  int i = blockIdx.x;
  int b0 = blockIdx.y * 8;
  int tid = threadIdx.x;
  int lane = tid & 63, wid = tid >> 6;
  const float* w_g = ws + WS_W;
  for (int t = tid; t < 512; t += 256) {
    int j = t >> 6, n = t & 63;
    wt[n][j] = w_g[(b0 + j) * 64 + n];
  }
  __syncthreads();
  const float* fi = feat + i * 32768;
  int f0 = tid * 2;
  float2 sc[8];
#pragma unroll
  for (int j = 0; j < 8; ++j) sc[j] = make_float2(0.f, 0.f);
  for (int n = 0; n < 64; n += 8) {
    float2 fv[8];
#pragma unroll
    for (int t = 0; t < 8; ++t)
      fv[t] = *reinterpret_cast<const float2*>(&fi[(n + t) * 512 + f0]);
#pragma unroll
    for (int t = 0; t < 8; ++t) {
      const float4* wp = reinterpret_cast<const float4*>(&wt[n + t][0]);
      float4 w0 = wp[0], w1 = wp[1];
      sc[0].x += w0.x * fv[t].x; sc[0].y += w0.x * fv[t].y;
      sc[1].x += w0.y * fv[t].x; sc[1].y += w0.y * fv[t].y;
      sc[2].x += w0.z * fv[t].x; sc[2].y += w0.z * fv[t].y;
      sc[3].x += w0.w * fv[t].x; sc[3].y += w0.w * fv[t].y;
      sc[4].x += w1.x * fv[t].x; sc[4].y += w1.x * fv[t].y;
      sc[5].x += w1.y * fv[t].x; sc[5].y += w1.y * fv[t].y;
      sc[6].x += w1.z * fv[t].x; sc[6].y += w1.z * fv[t].y;
      sc[7].x += w1.w * fv[t].x; sc[7].y += w1.w * fv[t].y;
    }
  }
  float m[8];
#pragma unroll
  for (int j = 0; j < 8; ++j) m[j] = fmaxf(sc[j].x, sc[j].y);
  for (int d = 1; d < 64; d <<= 1) {
#pragma unroll
    for (int j = 0; j < 8; ++j) m[j] = fmaxf(m[j], __shfl_xor(m[j], d));
  }
  if (lane == 0) {
#pragma unroll
    for (int j = 0; j < 8; ++j) red[wid * 8 + j] = m[j];
  }
  __syncthreads();
#pragma unroll
  for (int j = 0; j < 8; ++j)
    m[j] = fmaxf(fmaxf(red[j], red[8 + j]), fmaxf(red[16 + j], red[24 + j]));
  __syncthreads();
  float sm[8];
#pragma unroll
  for (int j = 0; j < 8; ++j) {
    sc[j].x = __expf(sc[j].x - m[j]);
    sc[j].y = __expf(sc[j].y - m[j]);
    sm[j] = sc[j].x + sc[j].y;
  }
  for (int d = 1; d < 64; d <<= 1) {
#pragma unroll
    for (int j = 0; j < 8; ++j) sm[j] += __shfl_xor(sm[j], d);
  }
  if (lane == 0) {
#pragma unroll
    for (int j = 0; j < 8; ++j) red[wid * 8 + j] = sm[j];
  }
  __syncthreads();
#pragma unroll
  for (int j = 0; j < 8; ++j)
    sm[j] = (red[j] + red[8 + j]) + (red[16 + j] + red[24 + j]);
  float2 ctx = make_float2(0.f, 0.f);
#pragma unroll
  for (int j = 0; j < 8; ++j) {
    float is = 1.f / sm[j];
    float ax = sc[j].x * is, ay = sc[j].y * is;
    *reinterpret_cast<float2*>(&out[OUT_AW + (i * 64 + b0 + j) * 512 + f0]) =
        make_float2(ax, ay);
    float2 fb = *reinterpret_cast<const float2*>(&fi[(b0 + j) * 512 + f0]);
    ctx.x += ax * fb.x;
    ctx.y += ay * fb.y;
  }
  float* ctxp = ws + WS_CTX + i * 512 + f0;
  atomicAdd(&ctxp[0], ctx.x);
  atomicAdd(&ctxp[1], ctx.y);
}

// -------------- K5: z += [ctx|ye|h] @ [Wx;Wh]  grid (16 tiles of 256, 16 k-splits)
// Wave w: rows w*16..+15; lane: cols n0+lane*4 (lane-unique 1KB/inst).
// A = broadcast LDS reads. K=128 per block (single chunk).
__global__ __launch_bounds__(256) void k5_zgemm(const float* __restrict__ h,
    const float* __restrict__ Wx, const float* __restrict__ Wh,
    float* __restrict__ ws) {
  __shared__ float At[128][68];
  int n0 = blockIdx.x * 256;
  int kc = blockIdx.y * 128;
  int tid = threadIdx.x;
  int lane = tid & 63, r0 = (tid >> 6) * 16;
  const float* src; int stride; int koff;
  if (kc < 512)       { src = ws + WS_CTX; stride = 512;  koff = kc; }
  else if (kc < 1024) { src = ws + WS_YE;  stride = 512;  koff = kc - 512; }
  else                { src = h;           stride = 1024; koff = kc - 1024; }
  for (int it = 0; it < 32; ++it) {
    int idx = tid + it * 256;        // 8192
    int k_l = idx & 127, b = idx >> 7;
    At[k_l][b] = src[b * stride + koff + k_l];
  }
  __syncthreads();
  const float* wp = ((kc < 1024) ? (Wx + (size_t)kc * 4096)
                                 : (Wh + (size_t)(kc - 1024) * 4096))
                    + n0 + lane * 4;
  float4 acc[16];
#pragma unroll
  for (int j = 0; j < 16; ++j) acc[j] = make_float4(0.f, 0.f, 0.f, 0.f);
  float4 wv0[8], wv1[8];
#pragma unroll
  for (int t = 0; t < 8; ++t)
    wv0[t] = *reinterpret_cast<const float4*>(wp + (size_t)t * 4096);
  for (int kb = 0; kb < 128; kb += 16) {
#pragma unroll
    for (int t = 0; t < 8; ++t)
      wv1[t] = *reinterpret_cast<const float4*>(wp + (size_t)(kb + 8 + t) * 4096);
#pragma unroll
    for (int t = 0; t < 8; ++t) {
      const float4* ap = reinterpret_cast<const float4*>(&At[kb + t][r0]);
      float4 a0 = ap[0], a1 = ap[1], a2 = ap[2], a3 = ap[3];
      FMA16(wv0[t], a0, a1, a2, a3)
    }
    if (kb + 16 < 128) {
#pragma unroll
      for (int t = 0; t < 8; ++t)
        wv0[t] = *reinterpret_cast<const float4*>(wp + (size_t)(kb + 16 + t) * 4096);
    }
#pragma unroll
    for (int t = 0; t < 8; ++t) {
      const float4* ap = reinterpret_cast<const float4*>(&At[kb + 8 + t][r0]);
      float4 a0 = ap[0], a1 = ap[1], a2 = ap[2], a3 = ap[3];
      FMA16(wv1[t], a0, a1, a2, a3)
    }
  }
  float* zp = ws + WS_Z + (size_t)r0 * 4096 + n0 + lane * 4;
#pragma unroll
  for (int j = 0; j < 16; ++j) {
    atomicAdd(&zp[(size_t)j * 4096 + 0], acc[j].x);
    atomicAdd(&zp[(size_t)j * 4096 + 1], acc[j].y);
    atomicAdd(&zp[(size_t)j * 4096 + 2], acc[j].z);
    atomicAdd(&zp[(size_t)j * 4096 + 3], acc[j].w);
  }
}

// -------------------------------- K6: LSTM gates -> h_new (x2), c_new
__global__ __launch_bounds__(256) void k6_gates(const float* __restrict__ ws,
    const float* __restrict__ c, float* __restrict__ out) {
  int idx = blockIdx.x * 256 + threadIdx.x;   // 65536
  int b = idx >> 10, u = idx & 1023;
  const float* z = ws + WS_Z;
  float zi = z[b * 4096 + u];
  float zf = z[b * 4096 + 1024 + u];
  float zg = z[b * 4096 + 2048 + u];
  float zo = z[b * 4096 + 3072 + u];
  float ig = 1.f / (1.f + __expf(-zi));
  float fg = 1.f / (1.f + __expf(-zf));
  float gg = tanhf(zg);
  float og = 1.f / (1.f + __expf(-zo));
  float cn = fg * c[idx] + ig * gg;
  float hn = og * tanhf(cn);
  out[OUT_H1 + idx] = hn;
  out[OUT_H2 + idx] = hn;
  out[OUT_C + idx] = cn;
}

// -------------------- K7: t1 += h_new @ W1, grid (16 n-tiles of 64, 16 k-splits of 64)
__global__ __launch_bounds__(256) void k7_t1gemm(const float* __restrict__ out_r,
    const float* __restrict__ W1, float* __restrict__ ws) {
  __shared__ float At[64][68];
  int n0 = blockIdx.x * 64;
  int k0 = blockIdx.y * 64;
  int tid = threadIdx.x;
  const float* hn = out_r + OUT_H1;
  for (int it = 0; it < 16; ++it) {
    int idx = tid + it * 256;          // 4096
    int k_l = idx & 63, b = idx >> 6;
    At[k_l][b] = hn[b * 1024 + k0 + k_l];
  }
  __syncthreads();
  int ng = tid & 15, g = tid >> 4;     // 16 col-groups x4, 16 row-groups x4
  const float* wp = W1 + (size_t)k0 * 1024 + n0 + ng * 4;
  float4 acc[4];
#pragma unroll
  for (int j = 0; j < 4; ++j) acc[j] = make_float4(0.f, 0.f, 0.f, 0.f);
  for (int kb = 0; kb < 64; kb += 8) {
    float4 wv[8];
#pragma unroll
    for (int t = 0; t < 8; ++t)
      wv[t] = *reinterpret_cast<const float4*>(wp + (size_t)(kb + t) * 1024);
#pragma unroll
    for (int t = 0; t < 8; ++t) {
      float4 a0 = *reinterpret_cast<const float4*>(&At[kb + t][g * 4]);
      FMA4(acc[0], a0.x, wv[t]) FMA4(acc[1], a0.y, wv[t])
      FMA4(acc[2], a0.z, wv[t]) FMA4(acc[3], a0.w, wv[t])
    }
  }
  float* t1 = ws + WS_T1 + (size_t)(g * 4) * 1024 + n0 + ng * 4;
#pragma unroll
  for (int j = 0; j < 4; ++j) {
    atomicAdd(&t1[(size_t)j * 1024 + 0], acc[j].x);
    atomicAdd(&t1[(size_t)j * 1024 + 1], acc[j].y);
    atomicAdd(&t1[(size_t)j * 1024 + 2], acc[j].z);
    atomicAdd(&t1[(size_t)j * 1024 + 3], acc[j].w);
  }
}

// -------------------- K8: logits += t1 @ W2, grid (125 tiles of 256, 4 k-splits)
// Wave w: rows w*16..+15; lane: cols n0+lane*4 (lane-unique 1KB/inst).
// A = broadcast LDS reads. K=256 per block (2 chunks of 128). 8-deep ping-pong.
__global__ __launch_bounds__(256) void k8_logits(const float* __restrict__ W2,
    const float* __restrict__ wsr, float* __restrict__ out) {
  __shared__ float At[128][68];
  int n0 = blockIdx.x * 256;
  int k0b = blockIdx.y * 256;
  int tid = threadIdx.x;
  int lane = tid & 63, r0 = (tid >> 6) * 16;
  const float* t1 = wsr + WS_T1;
  float4 acc[16];
#pragma unroll
  for (int j = 0; j < 16; ++j) acc[j] = make_float4(0.f, 0.f, 0.f, 0.f);
  for (int s = 0; s < 2; ++s) {
    int kc = k0b + s * 128;
    if (s) __syncthreads();
    for (int it = 0; it < 32; ++it) {
      int idx = tid + it * 256;        // 8192
      int k_l = idx & 127, b = idx >> 7;
      At[k_l][b] = t1[b * 1024 + kc + k_l];
    }
    __syncthreads();
    const float* wp = W2 + (size_t)kc * 32000 + n0 + lane * 4;
    float4 wv0[8], wv1[8];
#pragma unroll
    for (int t = 0; t < 8; ++t)
      wv0[t] = *reinterpret_cast<const float4*>(wp + (size_t)t * 32000);
    for (int kb = 0; kb < 128; kb += 16) {
#pragma unroll
      for (int t = 0; t < 8; ++t)
        wv1[t] = *reinterpret_cast<const float4*>(wp + (size_t)(kb + 8 + t) * 32000);
#pragma unroll
      for (int t = 0; t < 8; ++t) {
        const float4* ap = reinterpret_cast<const float4*>(&At[kb + t][r0]);
        float4 a0 = ap[0], a1 = ap[1], a2 = ap[2], a3 = ap[3];
        FMA16(wv0[t], a0, a1, a2, a3)
      }
      if (kb + 16 < 128) {
#pragma unroll
        for (int t = 0; t < 8; ++t)
          wv0[t] = *reinterpret_cast<const float4*>(wp + (size_t)(kb + 16 + t) * 32000);
      }
#pragma unroll
      for (int t = 0; t < 8; ++t) {
        const float4* ap = reinterpret_cast<const float4*>(&At[kb + 8 + t][r0]);
        float4 a0 = ap[0], a1 = ap[1], a2 = ap[2], a3 = ap[3];
        FMA16(wv1[t], a0, a1, a2, a3)
      }
    }
  }
  float* op = out + OUT_LOGITS + (size_t)r0 * 32000 + n0 + lane * 4;
#pragma unroll
  for (int j = 0; j < 16; ++j) {
    atomicAdd(&op[(size_t)j * 32000 + 0], acc[j].x);
    atomicAdd(&op[(size_t)j * 32000 + 1], acc[j].y);
    atomicAdd(&op[(size_t)j * 32000 + 2], acc[j].z);
    atomicAdd(&op[(size_t)j * 32000 + 3], acc[j].w);
  }
}

extern "C" void kernel_launch(void* const* d_in, const int* in_sizes, int n_in,
                              void* d_out, int out_size, void* d_ws, size_t ws_size,
                              hipStream_t stream) {
  const int*   y    = (const int*)  d_in[0];
  const float* feat = (const float*)d_in[1];
  const float* so   = (const float*)d_in[2];
  const float* h    = (const float*)d_in[3];
  const float* c    = (const float*)d_in[4];
  const float* Q    = (const float*)d_in[5];
  const float* Katt = (const float*)d_in[6];
  const float* emb  = (const float*)d_in[7];
  const float* Wx   = (const float*)d_in[8];
  const float* Wh   = (const float*)d_in[9];
  const float* bl   = (const float*)d_in[10];
  const float* W1   = (const float*)d_in[11];
  const float* b1   = (const float*)d_in[12];
  const float* W2   = (const float*)d_in[13];
  const float* b2   = (const float*)d_in[14];
  float* ws  = (float*)d_ws;
  float* out = (float*)d_out;

  k0_init  <<<256, 256, 0, stream>>>(y, emb, bl, b1, ws);
  kb2_init <<<dim3(125, 4), 256, 0, stream>>>(b2, out);
  k1_sgemm <<<dim3(16, 16), 256, 0, stream>>>(so, Q, ws);
  k2_wgemm <<<16, 256, 0, stream>>>(Katt, ws);
  k3_attn  <<<dim3(64, 8), 256, 0, stream>>>(feat, ws, out);
  k5_zgemm <<<dim3(16, 16), 256, 0, stream>>>(h, Wx, Wh, ws);
  k6_gates <<<256, 256, 0, stream>>>(ws, c, out);
  k7_t1gemm<<<dim3(16, 16), 256, 0, stream>>>(out, W1, ws);
  k8_logits<<<dim3(125, 4), 256, 0, stream>>>(W2, ws, out);
}

// Round 9
// 409.740 us; speedup vs baseline: 1.2476x; 1.2476x over previous
//
#include <hip/hip_runtime.h>
#include <math.h>

// Problem dims: B=64, N=64, F=512, E=512, U=1024, V=32000
// ws layout (float offsets) — 462848 floats total (1.81 MB)
#define WS_S    0         // s = so @ Q^T (64x1024); dead after k2
#define WS_T1T  0         // t1^T [1024][64], init by k6, filled by k7 (reuses S)
#define WS_W    65536     // w = s @ K               (64 x 64)
#define WS_XT   69632     // x^T [2048][64]: rows 0-511 ctx^T, 512-1023 ye^T, 1024-2047 h^T
#define WS_Z    200704    // z = x@Wx + h@Wh + b     (64 x 4096)

// d_out layout (float offsets): (logits, h_new, h_new, c_new, aw)
#define OUT_LOGITS 0
#define OUT_H1     2048000
#define OUT_H2     2113536
#define OUT_C      2179072
#define OUT_AW     2244608

#define FMA4(ACC, A, W) { ACC.x += (A)*(W).x; ACC.y += (A)*(W).y; \
                          ACC.z += (A)*(W).z; ACC.w += (A)*(W).w; }

// 16 rows x 4 cols: A0..A3 = rows r0..r0+15 (broadcast), WV = 4 lane-cols
#define FMA16(WV, A0, A1, A2, A3) { \
    FMA4(acc[0],  A0.x, WV) FMA4(acc[1],  A0.y, WV) \
    FMA4(acc[2],  A0.z, WV) FMA4(acc[3],  A0.w, WV) \
    FMA4(acc[4],  A1.x, WV) FMA4(acc[5],  A1.y, WV) \
    FMA4(acc[6],  A1.z, WV) FMA4(acc[7],  A1.w, WV) \
    FMA4(acc[8],  A2.x, WV) FMA4(acc[9],  A2.y, WV) \
    FMA4(acc[10], A2.z, WV) FMA4(acc[11], A2.w, WV) \
    FMA4(acc[12], A3.x, WV) FMA4(acc[13], A3.y, WV) \
    FMA4(acc[14], A3.z, WV) FMA4(acc[15], A3.w, WV) }

// ---------------------------------------------------------------- K0: init
// s=0, w=0, ctx^T=0, ye^T=emb[y]^T, h^T, z=b_lstm.
__global__ __launch_bounds__(256) void k0_init(const int* __restrict__ y,
    const float* __restrict__ emb, const float* __restrict__ b_lstm,
    const float* __restrict__ h, float* __restrict__ ws) {
  int idx = blockIdx.x * 256 + threadIdx.x;      // 65536
  ws[WS_S + idx] = 0.f;
  *reinterpret_cast<float4*>(&ws[WS_Z + idx * 4]) =
      *reinterpret_cast<const float4*>(&b_lstm[(idx * 4) & 4095]);
  // h^T: read h coalesced, scatter-write
  ws[WS_XT + (size_t)(1024 + (idx & 1023)) * 64 + (idx >> 10)] = h[idx];
  if (idx < 32768) {
    ws[WS_XT + idx] = 0.f;                       // ctx^T rows 0..511
    int b = idx >> 9, e = idx & 511;
    ws[WS_XT + (size_t)(512 + e) * 64 + b] = emb[(size_t)y[b] * 512 + e];
  }
  if (idx < 4096) ws[WS_W + idx] = 0.f;
}

// ------------------------------------------------- K1: s += so @ Q^T (atomic split-K)
__global__ __launch_bounds__(256) void k1_sgemm(const float* __restrict__ so,
    const float* __restrict__ Q, float* __restrict__ ws) {
  __shared__ float Qt[64][65];    // [k_l][u_l]
  __shared__ float SOt[64][68];   // [k_l][b]
  int u0 = blockIdx.x * 64;
  int k0 = blockIdx.y * 64;
  int tid = threadIdx.x;
  for (int i = 0; i < 16; ++i) {
    int idx = tid + i * 256;
    int r = idx >> 6, k_l = idx & 63;
    Qt[k_l][r]  = Q[(u0 + r) * 1024 + k0 + k_l];
    SOt[k_l][r] = so[r * 1024 + k0 + k_l];
  }
  __syncthreads();
  int u = tid & 63, g = tid >> 6;
  float acc[16];
#pragma unroll
  for (int j = 0; j < 16; ++j) acc[j] = 0.f;
  for (int k_l = 0; k_l < 64; ++k_l) {
    float qv = Qt[k_l][u];
    const float4* sp = reinterpret_cast<const float4*>(&SOt[k_l][g * 16]);
    float4 s0 = sp[0], s1 = sp[1], s2 = sp[2], s3 = sp[3];
    acc[0]  += s0.x * qv; acc[1]  += s0.y * qv; acc[2]  += s0.z * qv; acc[3]  += s0.w * qv;
    acc[4]  += s1.x * qv; acc[5]  += s1.y * qv; acc[6]  += s1.z * qv; acc[7]  += s1.w * qv;
    acc[8]  += s2.x * qv; acc[9]  += s2.y * qv; acc[10] += s2.z * qv; acc[11] += s2.w * qv;
    acc[12] += s3.x * qv; acc[13] += s3.y * qv; acc[14] += s3.z * qv; acc[15] += s3.w * qv;
  }
  float* s_out = ws + WS_S;
#pragma unroll
  for (int j = 0; j < 16; ++j)
    atomicAdd(&s_out[(g * 16 + j) * 1024 + u0 + u], acc[j]);
}

// ------------------------------------------------- K2: w += s @ K (atomic split-K)
__global__ __launch_bounds__(256) void k2_wgemm(const float* __restrict__ Katt,
    float* __restrict__ ws) {
  __shared__ float St[64][68];
  __shared__ float Kl[64][65];
  int k0 = blockIdx.x * 64;
  int tid = threadIdx.x;
  const float* s_in = ws + WS_S;
  for (int i = 0; i < 16; ++i) {
    int idx = tid + i * 256;
    int r = idx >> 6, q = idx & 63;
    St[q][r] = s_in[r * 1024 + k0 + q];
    Kl[r][q] = Katt[(k0 + r) * 64 + q];
  }
  __syncthreads();
  int n = tid & 63, g = tid >> 6;
  float acc[16];
#pragma unroll
  for (int j = 0; j < 16; ++j) acc[j] = 0.f;
  for (int k_l = 0; k_l < 64; ++k_l) {
    float kv = Kl[k_l][n];
    const float4* sp = reinterpret_cast<const float4*>(&St[k_l][g * 16]);
    float4 s0 = sp[0], s1 = sp[1], s2 = sp[2], s3 = sp[3];
    acc[0]  += s0.x * kv; acc[1]  += s0.y * kv; acc[2]  += s0.z * kv; acc[3]  += s0.w * kv;
    acc[4]  += s1.x * kv; acc[5]  += s1.y * kv; acc[6]  += s1.z * kv; acc[7]  += s1.w * kv;
    acc[8]  += s2.x * kv; acc[9]  += s2.y * kv; acc[10] += s2.z * kv; acc[11] += s2.w * kv;
    acc[12] += s3.x * kv; acc[13] += s3.y * kv; acc[14] += s3.z * kv; acc[15] += s3.w * kv;
  }
  float* w_out = ws + WS_W;
#pragma unroll
  for (int j = 0; j < 16; ++j)
    atomicAdd(&w_out[(g * 16 + j) * 64 + n], acc[j]);
}

// ---------------- K3: scores->softmax->aw + context^T. grid (i=64, set=8), 256 thr
__global__ __launch_bounds__(256) void k3_attn(const float* __restrict__ feat,
    float* __restrict__ ws, float* __restrict__ out) {
  __shared__ float wt[64][8];     // [n][j]
  __shared__ float red[32];       // 4 waves x 8
  int i = blockIdx.x;
  int b0 = blockIdx.y * 8;
  int tid = threadIdx.x;
  int lane = tid & 63, wid = tid >> 6;
  const float* w_g = ws + WS_W;
  for (int t = tid; t < 512; t += 256) {
    int j = t >> 6, n = t & 63;
    wt[n][j] = w_g[(b0 + j) * 64 + n];
  }
  __syncthreads();
  const float* fi = feat + i * 32768;
  int f0 = tid * 2;
  float2 sc[8];
#pragma unroll
  for (int j = 0; j < 8; ++j) sc[j] = make_float2(0.f, 0.f);
  for (int n = 0; n < 64; n += 8) {
    float2 fv[8];
#pragma unroll
    for (int t = 0; t < 8; ++t)
      fv[t] = *reinterpret_cast<const float2*>(&fi[(n + t) * 512 + f0]);
#pragma unroll
    for (int t = 0; t < 8; ++t) {
      const float4* wp = reinterpret_cast<const float4*>(&wt[n + t][0]);
      float4 w0 = wp[0], w1 = wp[1];
      sc[0].x += w0.x * fv[t].x; sc[0].y += w0.x * fv[t].y;
      sc[1].x += w0.y * fv[t].x; sc[1].y += w0.y * fv[t].y;
      sc[2].x += w0.z * fv[t].x; sc[2].y += w0.z * fv[t].y;
      sc[3].x += w0.w * fv[t].x; sc[3].y += w0.w * fv[t].y;
      sc[4].x += w1.x * fv[t].x; sc[4].y += w1.x * fv[t].y;
      sc[5].x += w1.y * fv[t].x; sc[5].y += w1.y * fv[t].y;
      sc[6].x += w1.z * fv[t].x; sc[6].y += w1.z * fv[t].y;
      sc[7].x += w1.w * fv[t].x; sc[7].y += w1.w * fv[t].y;
    }
  }
  float m[8];
#pragma unroll
  for (int j = 0; j < 8; ++j) m[j] = fmaxf(sc[j].x, sc[j].y);
  for (int d = 1; d < 64; d <<= 1) {
#pragma unroll
    for (int j = 0; j < 8; ++j) m[j] = fmaxf(m[j], __shfl_xor(m[j], d));
  }
  if (lane == 0) {
#pragma unroll
    for (int j = 0; j < 8; ++j) red[wid * 8 + j] = m[j];
  }
  __syncthreads();
#pragma unroll
  for (int j = 0; j < 8; ++j)
    m[j] = fmaxf(fmaxf(red[j], red[8 + j]), fmaxf(red[16 + j], red[24 + j]));
  __syncthreads();
  float sm[8];
#pragma unroll
  for (int j = 0; j < 8; ++j) {
    sc[j].x = __expf(sc[j].x - m[j]);
    sc[j].y = __expf(sc[j].y - m[j]);
    sm[j] = sc[j].x + sc[j].y;
  }
  for (int d = 1; d < 64; d <<= 1) {
#pragma unroll
    for (int j = 0; j < 8; ++j) sm[j] += __shfl_xor(sm[j], d);
  }
  if (lane == 0) {
#pragma unroll
    for (int j = 0; j < 8; ++j) red[wid * 8 + j] = sm[j];
  }
  __syncthreads();
#pragma unroll
  for (int j = 0; j < 8; ++j)
    sm[j] = (red[j] + red[8 + j]) + (red[16 + j] + red[24 + j]);
  float2 ctx = make_float2(0.f, 0.f);
#pragma unroll
  for (int j = 0; j < 8; ++j) {
    float is = 1.f / sm[j];
    float ax = sc[j].x * is, ay = sc[j].y * is;
    *reinterpret_cast<float2*>(&out[OUT_AW + (size_t)(i * 64 + b0 + j) * 512 + f0]) =
        make_float2(ax, ay);
    float2 fb = *reinterpret_cast<const float2*>(&fi[(b0 + j) * 512 + f0]);
    ctx.x += ax * fb.x;
    ctx.y += ay * fb.y;
  }
  // ctx^T: row f, col i
  atomicAdd(&ws[WS_XT + (size_t)f0 * 64 + i], ctx.x);
  atomicAdd(&ws[WS_XT + (size_t)(f0 + 1) * 64 + i], ctx.y);
}

// -------------- K5: z += x^T-chunks @ [Wx;Wh]. grid (64 n-tiles of 64, 8 k-splits)
// Wave: rows r0=wid*16; lane = (kg = lane>>4, c4 = (lane&15)*4).
// Lane loads W[(k+kg)][n0+c4] float4 (64 unique/wave); A broadcast from LDS.
// Epilogue: shfl_xor(16,32) kg-reduce, then 16 scalar atomicAdds (kg-split rows).
__global__ __launch_bounds__(256) void k5_zgemm(const float* __restrict__ Wx,
    const float* __restrict__ Wh, float* __restrict__ ws) {
  __shared__ float At[128][68];
  int n0 = blockIdx.x * 64;
  int kbase = blockIdx.y * 256;
  int tid = threadIdx.x;
  int lane = tid & 63, r0 = (tid >> 6) * 16;
  int kg = lane >> 4, c4 = (lane & 15) * 4;
  const float* xT = ws + WS_XT;
  float4 acc[16];
#pragma unroll
  for (int j = 0; j < 16; ++j) acc[j] = make_float4(0.f, 0.f, 0.f, 0.f);
  for (int s = 0; s < 2; ++s) {
    int kc = kbase + s * 128;
    if (s) __syncthreads();
    for (int it = 0; it < 8; ++it) {       // stage 128x64 floats as float4
      int idx = tid + it * 256;            // 2048 float4
      int k_l = idx >> 4, f4 = (idx & 15) * 4;
      float4 v = *reinterpret_cast<const float4*>(xT + (size_t)(kc + k_l) * 64 + f4);
      *reinterpret_cast<float4*>(&At[k_l][f4]) = v;
    }
    __syncthreads();
    const float* wp = ((kc < 1024) ? (Wx + (size_t)kc * 4096)
                                   : (Wh + (size_t)(kc - 1024) * 4096))
                      + (size_t)kg * 4096 + n0 + c4;
    float4 wv0[8], wv1[8];
#pragma unroll
    for (int t = 0; t < 8; ++t)
      wv0[t] = *reinterpret_cast<const float4*>(wp + (size_t)(t * 4) * 4096);
    for (int kb = 0; kb < 32; kb += 16) {
#pragma unroll
      for (int t = 0; t < 8; ++t)
        wv1[t] = *reinterpret_cast<const float4*>(wp + (size_t)((kb + 8 + t) * 4) * 4096);
#pragma unroll
      for (int t = 0; t < 8; ++t) {
        const float4* ap = reinterpret_cast<const float4*>(&At[(kb + t) * 4 + kg][r0]);
        float4 a0 = ap[0], a1 = ap[1], a2 = ap[2], a3 = ap[3];
        FMA16(wv0[t], a0, a1, a2, a3)
      }
      if (kb + 16 < 32) {
#pragma unroll
        for (int t = 0; t < 8; ++t)
          wv0[t] = *reinterpret_cast<const float4*>(wp + (size_t)((kb + 16 + t) * 4) * 4096);
      }
#pragma unroll
      for (int t = 0; t < 8; ++t) {
        const float4* ap = reinterpret_cast<const float4*>(&At[(kb + 8 + t) * 4 + kg][r0]);
        float4 a0 = ap[0], a1 = ap[1], a2 = ap[2], a3 = ap[3];
        FMA16(wv1[t], a0, a1, a2, a3)
      }
    }
  }
#pragma unroll
  for (int j = 0; j < 16; ++j) {
    acc[j].x += __shfl_xor(acc[j].x, 16); acc[j].y += __shfl_xor(acc[j].y, 16);
    acc[j].z += __shfl_xor(acc[j].z, 16); acc[j].w += __shfl_xor(acc[j].w, 16);
    acc[j].x += __shfl_xor(acc[j].x, 32); acc[j].y += __shfl_xor(acc[j].y, 32);
    acc[j].z += __shfl_xor(acc[j].z, 32); acc[j].w += __shfl_xor(acc[j].w, 32);
  }
  float* zb = ws + WS_Z + n0 + c4;
#define ZST(J, RR) { float* p = zb + (size_t)(r0 + RR) * 4096; \
    atomicAdd(p, acc[J].x); atomicAdd(p + 1, acc[J].y); \
    atomicAdd(p + 2, acc[J].z); atomicAdd(p + 3, acc[J].w); }
  if (kg == 0)      { ZST(0, 0)  ZST(1, 1)  ZST(2, 2)   ZST(3, 3) }
  else if (kg == 1) { ZST(4, 4)  ZST(5, 5)  ZST(6, 6)   ZST(7, 7) }
  else if (kg == 2) { ZST(8, 8)  ZST(9, 9)  ZST(10, 10) ZST(11, 11) }
  else              { ZST(12, 12) ZST(13, 13) ZST(14, 14) ZST(15, 15) }
#undef ZST
}

// -------------------------------- K6: LSTM gates -> h_new (x2), c_new; t1^T = b1
__global__ __launch_bounds__(256) void k6_gates(float* __restrict__ ws,
    const float* __restrict__ c, const float* __restrict__ b1,
    float* __restrict__ out) {
  int idx = blockIdx.x * 256 + threadIdx.x;   // 65536
  int b = idx >> 10, u = idx & 1023;
  const float* z = ws + WS_Z;
  float zi = z[b * 4096 + u];
  float zf = z[b * 4096 + 1024 + u];
  float zg = z[b * 4096 + 2048 + u];
  float zo = z[b * 4096 + 3072 + u];
  float ig = 1.f / (1.f + __expf(-zi));
  float fg = 1.f / (1.f + __expf(-zf));
  float gg = tanhf(zg);
  float og = 1.f / (1.f + __expf(-zo));
  float cn = fg * c[idx] + ig * gg;
  float hn = og * tanhf(cn);
  out[OUT_H1 + idx] = hn;
  out[OUT_H2 + idx] = hn;
  out[OUT_C + idx] = cn;
  ws[WS_T1T + idx] = b1[idx >> 6];            // t1^T[n][b] = b1[n]
}

// -------------------- K7: t1^T += (h_new @ W1)^T, grid (16 n-tiles, 16 k-splits)
__global__ __launch_bounds__(256) void k7_t1gemm(const float* __restrict__ out_r,
    const float* __restrict__ W1, float* __restrict__ ws) {
  __shared__ float At[64][68];
  int n0 = blockIdx.x * 64;
  int k0 = blockIdx.y * 64;
  int tid = threadIdx.x;
  const float* hn = out_r + OUT_H1;
  for (int it = 0; it < 16; ++it) {
    int idx = tid + it * 256;          // 4096
    int k_l = idx & 63, b = idx >> 6;
    At[k_l][b] = hn[b * 1024 + k0 + k_l];
  }
  __syncthreads();
  int ng = tid & 15, g = tid >> 4;     // 16 col-groups x4, 16 row-groups x4
  const float* wp = W1 + (size_t)k0 * 1024 + n0 + ng * 4;
  float4 acc[4];
#pragma unroll
  for (int j = 0; j < 4; ++j) acc[j] = make_float4(0.f, 0.f, 0.f, 0.f);
  for (int kb = 0; kb < 64; kb += 8) {
    float4 wv[8];
#pragma unroll
    for (int t = 0; t < 8; ++t)
      wv[t] = *reinterpret_cast<const float4*>(wp + (size_t)(kb + t) * 1024);
#pragma unroll
    for (int t = 0; t < 8; ++t) {
      float4 a0 = *reinterpret_cast<const float4*>(&At[kb + t][g * 4]);
      FMA4(acc[0], a0.x, wv[t]) FMA4(acc[1], a0.y, wv[t])
      FMA4(acc[2], a0.z, wv[t]) FMA4(acc[3], a0.w, wv[t])
    }
  }
  // t1^T[n][b]: n = n0+ng*4+cc, b = g*4+j
  float* t1T = ws + WS_T1T;
#pragma unroll
  for (int j = 0; j < 4; ++j) {
    int b = g * 4 + j;
    atomicAdd(&t1T[(size_t)(n0 + ng * 4 + 0) * 64 + b], acc[j].x);
    atomicAdd(&t1T[(size_t)(n0 + ng * 4 + 1) * 64 + b], acc[j].y);
    atomicAdd(&t1T[(size_t)(n0 + ng * 4 + 2) * 64 + b], acc[j].z);
    atomicAdd(&t1T[(size_t)(n0 + ng * 4 + 3) * 64 + b], acc[j].w);
  }
}

// -------------------- K8: logits = t1 @ W2 + b2. grid 500 tiles of 64 cols, FULL K.
// Wave: rows r0=wid*16; lane = (kg, c4): lane-unique W2 float4 (1KB/wave-inst).
// kg-partial accumulation, shfl_xor(16,32) reduce, plain float4 stores + b2.
__global__ __launch_bounds__(256) void k8_logits(const float* __restrict__ W2,
    const float* __restrict__ b2, const float* __restrict__ wsr,
    float* __restrict__ out) {
  __shared__ float At[128][68];
  int n0 = blockIdx.x * 64;
  int tid = threadIdx.x;
  int lane = tid & 63, r0 = (tid >> 6) * 16;
  int kg = lane >> 4, c4 = (lane & 15) * 4;
  const float* t1T = wsr + WS_T1T;
  float4 bias = *reinterpret_cast<const float4*>(b2 + n0 + c4);
  const float* wbase = W2 + (size_t)kg * 32000 + n0 + c4;
  float4 acc[16];
#pragma unroll
  for (int j = 0; j < 16; ++j) acc[j] = make_float4(0.f, 0.f, 0.f, 0.f);
  for (int kc = 0; kc < 1024; kc += 128) {
    if (kc) __syncthreads();
    for (int it = 0; it < 8; ++it) {       // stage t1^T chunk as float4
      int idx = tid + it * 256;            // 2048 float4
      int k_l = idx >> 4, f4 = (idx & 15) * 4;
      float4 v = *reinterpret_cast<const float4*>(t1T + (size_t)(kc + k_l) * 64 + f4);
      *reinterpret_cast<float4*>(&At[k_l][f4]) = v;
    }
    __syncthreads();
    const float* wp = wbase + (size_t)kc * 32000;
    float4 wv0[8], wv1[8];
#pragma unroll
    for (int t = 0; t < 8; ++t)
      wv0[t] = *reinterpret_cast<const float4*>(wp + (size_t)(t * 4) * 32000);
    for (int kb = 0; kb < 32; kb += 16) {
#pragma unroll
      for (int t = 0; t < 8; ++t)
        wv1[t] = *reinterpret_cast<const float4*>(wp + (size_t)((kb + 8 + t) * 4) * 32000);
#pragma unroll
      for (int t = 0; t < 8; ++t) {
        const float4* ap = reinterpret_cast<const float4*>(&At[(kb + t) * 4 + kg][r0]);
        float4 a0 = ap[0], a1 = ap[1], a2 = ap[2], a3 = ap[3];
        FMA16(wv0[t], a0, a1, a2, a3)
      }
      if (kb + 16 < 32) {
#pragma unroll
        for (int t = 0; t < 8; ++t)
          wv0[t] = *reinterpret_cast<const float4*>(wp + (size_t)((kb + 16 + t) * 4) * 32000);
      }
#pragma unroll
      for (int t = 0; t < 8; ++t) {
        const float4* ap = reinterpret_cast<const float4*>(&At[(kb + 8 + t) * 4 + kg][r0]);
        float4 a0 = ap[0], a1 = ap[1], a2 = ap[2], a3 = ap[3];
        FMA16(wv1[t], a0, a1, a2, a3)
      }
    }
  }
#pragma unroll
  for (int j = 0; j < 16; ++j) {
    acc[j].x += __shfl_xor(acc[j].x, 16); acc[j].y += __shfl_xor(acc[j].y, 16);
    acc[j].z += __shfl_xor(acc[j].z, 16); acc[j].w += __shfl_xor(acc[j].w, 16);
    acc[j].x += __shfl_xor(acc[j].x, 32); acc[j].y += __shfl_xor(acc[j].y, 32);
    acc[j].z += __shfl_xor(acc[j].z, 32); acc[j].w += __shfl_xor(acc[j].w, 32);
  }
  float* ob = out + OUT_LOGITS + n0 + c4;
#define LST(J, RR) { float4 v = acc[J]; \
    v.x += bias.x; v.y += bias.y; v.z += bias.z; v.w += bias.w; \
    *reinterpret_cast<float4*>(ob + (size_t)(r0 + RR) * 32000) = v; }
  if (kg == 0)      { LST(0, 0)   LST(1, 1)   LST(2, 2)   LST(3, 3) }
  else if (kg == 1) { LST(4, 4)   LST(5, 5)   LST(6, 6)   LST(7, 7) }
  else if (kg == 2) { LST(8, 8)   LST(9, 9)   LST(10, 10) LST(11, 11) }
  else              { LST(12, 12) LST(13, 13) LST(14, 14) LST(15, 15) }
#undef LST
}

extern "C" void kernel_launch(void* const* d_in, const int* in_sizes, int n_in,
                              void* d_out, int out_size, void* d_ws, size_t ws_size,
                              hipStream_t stream) {
  const int*   y    = (const int*)  d_in[0];
  const float* feat = (const float*)d_in[1];
  const float* so   = (const float*)d_in[2];
  const float* h    = (const float*)d_in[3];
  const float* c    = (const float*)d_in[4];
  const float* Q    = (const float*)d_in[5];
  const float* Katt = (const float*)d_in[6];
  const float* emb  = (const float*)d_in[7];
  const float* Wx   = (const float*)d_in[8];
  const float* Wh   = (const float*)d_in[9];
  const float* bl   = (const float*)d_in[10];
  const float* W1   = (const float*)d_in[11];
  const float* b1   = (const float*)d_in[12];
  const float* W2   = (const float*)d_in[13];
  const float* b2   = (const float*)d_in[14];
  float* ws  = (float*)d_ws;
  float* out = (float*)d_out;

  k0_init  <<<256, 256, 0, stream>>>(y, emb, bl, h, ws);
  k1_sgemm <<<dim3(16, 16), 256, 0, stream>>>(so, Q, ws);
  k2_wgemm <<<16, 256, 0, stream>>>(Katt, ws);
  k3_attn  <<<dim3(64, 8), 256, 0, stream>>>(feat, ws, out);
  k5_zgemm <<<dim3(64, 8), 256, 0, stream>>>(Wx, Wh, ws);
  k6_gates <<<256, 256, 0, stream>>>(ws, c, b1, out);
  k7_t1gemm<<<dim3(16, 16), 256, 0, stream>>>(out, W1, ws);
  k8_logits<<<500, 256, 0, stream>>>(W2, b2, ws, out);
}